// Round 6
// baseline (304.365 us; speedup 1.0000x reference)
//
#include <hip/hip_runtime.h>
#include <hip/hip_bf16.h>

// GCN encoder: out = GCNconv2( relu(GCNconv1(x)) )
// GCNconv(h,W,b) = D^-1/2 (A+I) D^-1/2 (h W) + b
//
// R5: MFMA bf16 split-precision GEMMs (3-term: ah*bh + ah*bl + al*bh).
//   W pre-split into k-step-blocked bf16 hi/lo layout [ks][hl][g][n][8];
//   A (x / a1) loaded direct from global per lane, split in-register.
//   CSR build + lane-group gather agg unchanged from R4.

#define GCN_IN_C 256
#define GCN_HID  128
#define GCN_OUT  64

#define BKT_SHIFT 8
#define BKT_NODES 256
#define EPB 4096  // edges per block in partition kernels

typedef __bf16 bf16x8 __attribute__((ext_vector_type(8)));
typedef float f32x4 __attribute__((ext_vector_type(4)));

__global__ __launch_bounds__(256) void k_zero_i32(int* __restrict__ p, int n) {
  int i = blockIdx.x * 256 + threadIdx.x;
  if (i < n) p[i] = 0;
}

// P1a: bucket sizes
__global__ __launch_bounds__(256) void k_bucket_hist(const int* __restrict__ dst,
                                                     int* __restrict__ bcnt, int e, int nb) {
  __shared__ int h[512];
  int tid = threadIdx.x;
  h[tid] = 0; h[tid + 256] = 0;
  __syncthreads();
  int base = blockIdx.x * EPB;
#pragma unroll
  for (int j = 0; j < EPB / 256; ++j) {
    int i = base + j * 256 + tid;
    if (i < e) atomicAdd(&h[dst[i] >> BKT_SHIFT], 1);
  }
  __syncthreads();
  if (tid < nb && h[tid]) atomicAdd(&bcnt[tid], h[tid]);
  if (tid + 256 < nb && h[tid + 256]) atomicAdd(&bcnt[tid + 256], h[tid + 256]);
}

// exclusive scan of bucket sizes (nb <= 512), writes bbase and bcur
__global__ __launch_bounds__(512) void k_scan_buckets(const int* __restrict__ bcnt,
                                                      int* __restrict__ bbase,
                                                      int* __restrict__ bcur, int nb) {
  __shared__ int sh[512];
  int t = threadIdx.x;
  int v = (t < nb) ? bcnt[t] : 0;
  sh[t] = v;
  __syncthreads();
  for (int d = 1; d < 512; d <<= 1) {
    int x = (t >= d) ? sh[t - d] : 0;
    __syncthreads();
    sh[t] += x;
    __syncthreads();
  }
  if (t < nb) {
    int ex = sh[t] - v;
    bbase[t] = ex;
    bcur[t] = ex;
  }
}

// P1b: partition edges into bucket-contiguous regions (packed 4B)
__global__ __launch_bounds__(256) void k_partition(const int* __restrict__ src,
                                                   const int* __restrict__ dst,
                                                   int* __restrict__ bcur,
                                                   unsigned int* __restrict__ part,
                                                   int e, int nb) {
  __shared__ int h[512];
  __shared__ int base[512];
  int tid = threadIdx.x;
  h[tid] = 0; h[tid + 256] = 0;
  __syncthreads();
  int b0 = blockIdx.x * EPB;
  int s[EPB / 256], d[EPB / 256], rk[EPB / 256];
#pragma unroll
  for (int j = 0; j < EPB / 256; ++j) {
    int i = b0 + j * 256 + tid;
    if (i < e) {
      s[j] = src[i];
      d[j] = dst[i];
      rk[j] = atomicAdd(&h[d[j] >> BKT_SHIFT], 1);
    }
  }
  __syncthreads();
  if (tid < nb && h[tid]) base[tid] = atomicAdd(&bcur[tid], h[tid]);
  if (tid + 256 < nb && h[tid + 256]) base[tid + 256] = atomicAdd(&bcur[tid + 256], h[tid + 256]);
  __syncthreads();
#pragma unroll
  for (int j = 0; j < EPB / 256; ++j) {
    int i = b0 + j * 256 + tid;
    if (i < e) {
      int bk = d[j] >> BKT_SHIFT;
      unsigned int dl = (unsigned int)(d[j] & (BKT_NODES - 1));
      part[base[bk] + rk[j]] = (dl << 24) | (unsigned int)s[j];
    }
  }
}

// P2: per-bucket CSR finalize. One block per bucket.
__global__ __launch_bounds__(256) void k_bucket_csr(
    const unsigned int* __restrict__ part, const int* __restrict__ bbase,
    const int* __restrict__ bcnt, int* __restrict__ off, int* __restrict__ end,
    float* __restrict__ dis, int* __restrict__ csr, int n) {
  __shared__ int cnt[256];
  __shared__ int sc[256];
  __shared__ int cur[256];
  int b = blockIdx.x, tid = threadIdx.x;
  int node0 = b << BKT_SHIFT;
  int eb0 = bbase[b];
  int ebn = bcnt[b];
  cnt[tid] = 0;
  __syncthreads();
  for (int i = tid; i < ebn; i += 256) atomicAdd(&cnt[part[eb0 + i] >> 24], 1);
  __syncthreads();
  int v = cnt[tid];
  sc[tid] = v;
  __syncthreads();
  for (int dd = 1; dd < 256; dd <<= 1) {
    int x = (tid >= dd) ? sc[tid - dd] : 0;
    __syncthreads();
    sc[tid] += x;
    __syncthreads();
  }
  int lo = sc[tid] - v;  // exclusive
  cur[tid] = lo;
  int node = node0 + tid;
  if (node < n) {
    off[node] = eb0 + lo;
    end[node] = eb0 + lo + v;
    dis[node] = rsqrtf((float)v + 1.0f);
  }
  __syncthreads();
  for (int i = tid; i < ebn; i += 256) {
    unsigned int u = part[eb0 + i];
    int r = atomicAdd(&cur[u >> 24], 1);
    csr[eb0 + r] = (int)(u & 0xFFFFFFu);
  }
}

// Pre-split W (K x NOUT, f32) into k-step-blocked bf16 hi/lo:
//   Wsp[ks][hl][g][n][8] ; k = ks*32 + g*8 + j
template<int K, int NOUT>
__global__ __launch_bounds__(256) void k_split_w(const float* __restrict__ W,
                                                 __bf16* __restrict__ Wsp) {
  constexpr int KSTEPS = K / 32;
  int idx = blockIdx.x * 256 + threadIdx.x;  // (ks, g, n)
  if (idx >= KSTEPS * 4 * NOUT) return;
  int n = idx % NOUT;
  int g = (idx / NOUT) & 3;
  int ks = idx / (4 * NOUT);
  __bf16* hi = Wsp + (size_t)ks * (2 * 4 * NOUT * 8) + ((size_t)g * NOUT + n) * 8;
  __bf16* lo = hi + 4 * NOUT * 8;
#pragma unroll
  for (int j = 0; j < 8; ++j) {
    float f = W[(size_t)(ks * 32 + g * 8 + j) * NOUT + n];
    __bf16 h = (__bf16)f;
    hi[j] = h;
    lo[j] = (__bf16)(f - (float)h);
  }
}

// MFMA split-bf16 GEMM: T[m] = dis[m] * (X'[m] @ W), X' = relu(X+inb) if flagged.
// BM=128, 4 waves x 32 rows, full NOUT width. B staged in LDS (double buffer),
// A loaded direct from global per lane and split in-register.
template<int K, int NOUT, bool IN_RELU_BIAS>
__global__ __launch_bounds__(256) void k_gemm_mfma(
    const float* __restrict__ X, const __bf16* __restrict__ Wsp,
    const float* __restrict__ inb, const float* __restrict__ dis,
    float* __restrict__ T, int M) {
  constexpr int BM = 128;
  constexpr int NF = NOUT / 16;        // n-frags per wave
  constexpr int KSTEPS = K / 32;
  constexpr int TILE = 2 * 4 * NOUT * 8;   // bf16 elems per kstep (hi+lo)
  constexpr int GRAN = TILE * 2 / 16;      // 16B granules per kstep
  constexpr int GPT = GRAN / 256;          // granules per thread
  __shared__ __bf16 blds[2][TILE];

  const int tid = threadIdx.x;
  const int wave = tid >> 6;
  const int lane = tid & 63;
  const int l15 = lane & 15;
  const int lg = lane >> 4;                 // k-group 0..3
  const int r0w = blockIdx.x * BM + wave * 32;

  f32x4 acc[2][NF];
#pragma unroll
  for (int mf = 0; mf < 2; ++mf)
#pragma unroll
    for (int nf = 0; nf < NF; ++nf) acc[mf][nf] = (f32x4){0.f, 0.f, 0.f, 0.f};

  int rowA[2];
#pragma unroll
  for (int mf = 0; mf < 2; ++mf) {
    int r = r0w + mf * 16 + l15;
    rowA[mf] = (r < M) ? r : (M - 1);  // clamp: OOB rows never stored
  }

  const uint4* gW = (const uint4*)Wsp;
  // prologue: stage kstep 0 into buf 0
  {
    uint4* dst4 = (uint4*)&blds[0][0];
#pragma unroll
    for (int i = 0; i < GPT; ++i) dst4[tid + i * 256] = gW[tid + i * 256];
  }
  __syncthreads();

  int cur = 0;
  for (int ks = 0; ks < KSTEPS; ++ks) {
    uint4 sreg[GPT];
    if (ks + 1 < KSTEPS) {
#pragma unroll
      for (int i = 0; i < GPT; ++i)
        sreg[i] = gW[(size_t)(ks + 1) * GPT * 256 + tid + i * 256];
    }
    // ---- A fragments: load f32, optional relu+bias, split hi/lo in regs
    bf16x8 ah[2], al[2];
    const int k0 = ks * 32 + lg * 8;
#pragma unroll
    for (int mf = 0; mf < 2; ++mf) {
      const float* ap = X + (size_t)rowA[mf] * K + k0;
      float4 v0 = *(const float4*)ap;
      float4 v1 = *(const float4*)(ap + 4);
      float va[8] = {v0.x, v0.y, v0.z, v0.w, v1.x, v1.y, v1.z, v1.w};
      if (IN_RELU_BIAS) {
        float4 bb0 = *(const float4*)(inb + k0);
        float4 bb1 = *(const float4*)(inb + k0 + 4);
        float bb[8] = {bb0.x, bb0.y, bb0.z, bb0.w, bb1.x, bb1.y, bb1.z, bb1.w};
#pragma unroll
        for (int j = 0; j < 8; ++j) va[j] = fmaxf(va[j] + bb[j], 0.f);
      }
#pragma unroll
      for (int j = 0; j < 8; ++j) {
        __bf16 h = (__bf16)va[j];
        ah[mf][j] = h;
        al[mf][j] = (__bf16)(va[j] - (float)h);
      }
    }
    // ---- B fragments from LDS + MFMA (3-term split)
    const __bf16* bh_base = &blds[cur][0];
    const __bf16* bl_base = &blds[cur][4 * NOUT * 8];
    const int boff = lg * NOUT * 8 + l15 * 8;
#pragma unroll
    for (int nf = 0; nf < NF; ++nf) {
      bf16x8 bh = *(const bf16x8*)(bh_base + boff + nf * 128);
      bf16x8 bl = *(const bf16x8*)(bl_base + boff + nf * 128);
#pragma unroll
      for (int mf = 0; mf < 2; ++mf) {
        acc[mf][nf] = __builtin_amdgcn_mfma_f32_16x16x32_bf16(ah[mf], bh, acc[mf][nf], 0, 0, 0);
        acc[mf][nf] = __builtin_amdgcn_mfma_f32_16x16x32_bf16(ah[mf], bl, acc[mf][nf], 0, 0, 0);
        acc[mf][nf] = __builtin_amdgcn_mfma_f32_16x16x32_bf16(al[mf], bh, acc[mf][nf], 0, 0, 0);
      }
    }
    if (ks + 1 < KSTEPS) {
      uint4* dst4 = (uint4*)&blds[cur ^ 1][0];
#pragma unroll
      for (int i = 0; i < GPT; ++i) dst4[tid + i * 256] = sreg[i];
    }
    __syncthreads();
    cur ^= 1;
  }

  // ---- epilogue: C[col=l15, row=lg*4+r]; T[m] = dis[m] * acc
#pragma unroll
  for (int mf = 0; mf < 2; ++mf) {
    int rbase = r0w + mf * 16 + lg * 4;
    float dv[4];
#pragma unroll
    for (int r = 0; r < 4; ++r) dv[r] = (rbase + r < M) ? dis[rbase + r] : 0.f;
#pragma unroll
    for (int nf = 0; nf < NF; ++nf) {
#pragma unroll
      for (int r = 0; r < 4; ++r) {
        int rr = rbase + r;
        if (rr < M) T[(size_t)rr * NOUT + nf * 16 + l15] = dv[r] * acc[mf][nf][r];
      }
    }
  }
}

// CSR gather aggregation: wave per node, G lane-groups of LPG lanes,
// each group gathers full rows as float4, 2-deep unrolled edge stride.
template<int C, bool BIAS>
__global__ __launch_bounds__(256) void k_agg_csr(
    const int* __restrict__ csr, const int* __restrict__ off,
    const int* __restrict__ end, const float* __restrict__ ts,
    const float* __restrict__ dis, const float* __restrict__ bias,
    float* __restrict__ out, int n) {
  constexpr int LPG = C / 4;   // lanes per group
  constexpr int G = 64 / LPG;  // groups per wave
  int wid = (blockIdx.x * 256 + threadIdx.x) >> 6;
  int lane = threadIdx.x & 63;
  int gid = lane / LPG;
  int gl = lane % LPG;
  if (wid >= n) return;

  float4 acc = make_float4(0.f, 0.f, 0.f, 0.f);
  if (gid == 0) acc = *(const float4*)(ts + (size_t)wid * C + gl * 4);  // self term

  int e = off[wid] + gid;
  int e1 = end[wid];
  for (; e + G < e1; e += 2 * G) {
    int s0 = csr[e];
    int s1 = csr[e + G];
    float4 v0 = *(const float4*)(ts + (size_t)s0 * C + gl * 4);
    float4 v1 = *(const float4*)(ts + (size_t)s1 * C + gl * 4);
    acc.x += v0.x + v1.x;
    acc.y += v0.y + v1.y;
    acc.z += v0.z + v1.z;
    acc.w += v0.w + v1.w;
  }
  if (e < e1) {
    int s0 = csr[e];
    float4 v0 = *(const float4*)(ts + (size_t)s0 * C + gl * 4);
    acc.x += v0.x; acc.y += v0.y; acc.z += v0.z; acc.w += v0.w;
  }

#pragma unroll
  for (int w = LPG; w < 64; w <<= 1) {
    acc.x += __shfl_xor(acc.x, w);
    acc.y += __shfl_xor(acc.y, w);
    acc.z += __shfl_xor(acc.z, w);
    acc.w += __shfl_xor(acc.w, w);
  }

  if (gid == 0) {
    float di = dis[wid];
    float4 o;
    o.x = di * acc.x; o.y = di * acc.y; o.z = di * acc.z; o.w = di * acc.w;
    if (BIAS) {
      float4 bv = *(const float4*)(bias + gl * 4);
      o.x += bv.x; o.y += bv.y; o.z += bv.z; o.w += bv.w;
    }
    *(float4*)(out + (size_t)wid * C + gl * 4) = o;
  }
}

extern "C" void kernel_launch(void* const* d_in, const int* in_sizes, int n_in,
                              void* d_out, int out_size, void* d_ws, size_t ws_size,
                              hipStream_t stream) {
  const float* x  = (const float*)d_in[0];
  const int*   ei = (const int*)d_in[1];
  const float* W1 = (const float*)d_in[2];
  const float* b1 = (const float*)d_in[3];
  const float* W2 = (const float*)d_in[4];
  const float* b2 = (const float*)d_in[5];
  float* out = (float*)d_out;

  const int N = in_sizes[0] / GCN_IN_C;  // 100000
  const int E = in_sizes[1] / 2;         // 1600000
  const int* src = ei;
  const int* dst = ei + E;
  const int NB = (N + BKT_NODES - 1) >> BKT_SHIFT;  // 391 buckets
  const int EB = (E + EPB - 1) / EPB;               // partition blocks

  // ws layout:
  //   dis[N] | t1s[N*128] | a1[N*128] | off[N] | end[N] | csr[E]
  //   | bcnt|bbase|bcur [512 each] | w1sp | w2sp
  //   part[E] aliases a1 (dead before agg1 writes a1)
  char* p = (char*)d_ws;
  float* dis = (float*)p;             p += (size_t)N * 4;
  float* t1s = (float*)p;             p += (size_t)N * GCN_HID * 4;
  float* a1  = (float*)p;             p += (size_t)N * GCN_HID * 4;
  int* off   = (int*)p;               p += (size_t)N * 4;
  int* end   = (int*)p;               p += (size_t)N * 4;
  int* csr   = (int*)p;               p += (size_t)E * 4;
  int* bcnt  = (int*)p;               p += 512 * 4;
  int* bbase = (int*)p;               p += 512 * 4;
  int* bcur  = (int*)p;               p += 512 * 4;
  __bf16* w1sp = (__bf16*)p;          p += (size_t)(GCN_IN_C / 32) * 2 * 4 * GCN_HID * 8 * 2;
  __bf16* w2sp = (__bf16*)p;
  unsigned int* part = (unsigned int*)a1;  // alias
  float* t2s = t1s;

  // ---- weight pre-split (bf16 hi/lo, k-step-blocked)
  k_split_w<GCN_IN_C, GCN_HID>
      <<<((GCN_IN_C / 32) * 4 * GCN_HID + 255) / 256, 256, 0, stream>>>(W1, w1sp);
  k_split_w<GCN_HID, GCN_OUT>
      <<<((GCN_HID / 32) * 4 * GCN_OUT + 255) / 256, 256, 0, stream>>>(W2, w2sp);

  // ---- CSR build (bucketed counting sort)
  k_zero_i32<<<2, 256, 0, stream>>>(bcnt, 512);
  k_bucket_hist<<<EB, 256, 0, stream>>>(dst, bcnt, E, NB);
  k_scan_buckets<<<1, 512, 0, stream>>>(bcnt, bbase, bcur, NB);
  k_partition<<<EB, 256, 0, stream>>>(src, dst, bcur, part, E, NB);
  k_bucket_csr<<<NB, 256, 0, stream>>>(part, bbase, bcnt, off, end, dis, csr, N);

  // ---- layer 1
  k_gemm_mfma<GCN_IN_C, GCN_HID, false>
      <<<(N + 127) / 128, 256, 0, stream>>>(x, w1sp, nullptr, dis, t1s, N);
  k_agg_csr<GCN_HID, false>
      <<<((size_t)N * 64 + 255) / 256, 256, 0, stream>>>(csr, off, end, t1s, dis, nullptr, a1, N);

  // ---- layer 2
  k_gemm_mfma<GCN_HID, GCN_OUT, true>
      <<<(N + 127) / 128, 256, 0, stream>>>(a1, w2sp, b1, dis, t2s, N);
  k_agg_csr<GCN_OUT, true>
      <<<((size_t)N * 64 + 255) / 256, 256, 0, stream>>>(csr, off, end, t2s, dis, b2, out, N);
}

// Round 7
// 232.087 us; speedup vs baseline: 1.3114x; 1.3114x over previous
//
#include <hip/hip_runtime.h>
#include <hip/hip_bf16.h>

// GCN encoder: out = GCNconv2( relu(GCNconv1(x)) )
// GCNconv(h,W,b) = D^-1/2 (A+I) D^-1/2 (h W) + b
//
// R6: bf16 gather tables (halve aggregation bytes).
//   gemm (MFMA, split bf16 3-term) writes t_s = dis*(X'@W) as bf16;
//   agg gathers bf16 rows (16B/lane), accumulates f32, writes f32.
//   CSR build unchanged from R3/R4.

#define GCN_IN_C 256
#define GCN_HID  128
#define GCN_OUT  64

#define BKT_SHIFT 8
#define BKT_NODES 256
#define EPB 4096  // edges per block in partition kernels

typedef __bf16 bf16x8 __attribute__((ext_vector_type(8)));
typedef float f32x4 __attribute__((ext_vector_type(4)));

__global__ __launch_bounds__(256) void k_zero_i32(int* __restrict__ p, int n) {
  int i = blockIdx.x * 256 + threadIdx.x;
  if (i < n) p[i] = 0;
}

// P1a: bucket sizes
__global__ __launch_bounds__(256) void k_bucket_hist(const int* __restrict__ dst,
                                                     int* __restrict__ bcnt, int e, int nb) {
  __shared__ int h[512];
  int tid = threadIdx.x;
  h[tid] = 0; h[tid + 256] = 0;
  __syncthreads();
  int base = blockIdx.x * EPB;
#pragma unroll
  for (int j = 0; j < EPB / 256; ++j) {
    int i = base + j * 256 + tid;
    if (i < e) atomicAdd(&h[dst[i] >> BKT_SHIFT], 1);
  }
  __syncthreads();
  if (tid < nb && h[tid]) atomicAdd(&bcnt[tid], h[tid]);
  if (tid + 256 < nb && h[tid + 256]) atomicAdd(&bcnt[tid + 256], h[tid + 256]);
}

// exclusive scan of bucket sizes (nb <= 512), writes bbase and bcur
__global__ __launch_bounds__(512) void k_scan_buckets(const int* __restrict__ bcnt,
                                                      int* __restrict__ bbase,
                                                      int* __restrict__ bcur, int nb) {
  __shared__ int sh[512];
  int t = threadIdx.x;
  int v = (t < nb) ? bcnt[t] : 0;
  sh[t] = v;
  __syncthreads();
  for (int d = 1; d < 512; d <<= 1) {
    int x = (t >= d) ? sh[t - d] : 0;
    __syncthreads();
    sh[t] += x;
    __syncthreads();
  }
  if (t < nb) {
    int ex = sh[t] - v;
    bbase[t] = ex;
    bcur[t] = ex;
  }
}

// P1b: partition edges into bucket-contiguous regions (packed 4B)
__global__ __launch_bounds__(256) void k_partition(const int* __restrict__ src,
                                                   const int* __restrict__ dst,
                                                   int* __restrict__ bcur,
                                                   unsigned int* __restrict__ part,
                                                   int e, int nb) {
  __shared__ int h[512];
  __shared__ int base[512];
  int tid = threadIdx.x;
  h[tid] = 0; h[tid + 256] = 0;
  __syncthreads();
  int b0 = blockIdx.x * EPB;
  int s[EPB / 256], d[EPB / 256], rk[EPB / 256];
#pragma unroll
  for (int j = 0; j < EPB / 256; ++j) {
    int i = b0 + j * 256 + tid;
    if (i < e) {
      s[j] = src[i];
      d[j] = dst[i];
      rk[j] = atomicAdd(&h[d[j] >> BKT_SHIFT], 1);
    }
  }
  __syncthreads();
  if (tid < nb && h[tid]) base[tid] = atomicAdd(&bcur[tid], h[tid]);
  if (tid + 256 < nb && h[tid + 256]) base[tid + 256] = atomicAdd(&bcur[tid + 256], h[tid + 256]);
  __syncthreads();
#pragma unroll
  for (int j = 0; j < EPB / 256; ++j) {
    int i = b0 + j * 256 + tid;
    if (i < e) {
      int bk = d[j] >> BKT_SHIFT;
      unsigned int dl = (unsigned int)(d[j] & (BKT_NODES - 1));
      part[base[bk] + rk[j]] = (dl << 24) | (unsigned int)s[j];
    }
  }
}

// P2: per-bucket CSR finalize. One block per bucket.
__global__ __launch_bounds__(256) void k_bucket_csr(
    const unsigned int* __restrict__ part, const int* __restrict__ bbase,
    const int* __restrict__ bcnt, int* __restrict__ off, int* __restrict__ end,
    float* __restrict__ dis, int* __restrict__ csr, int n) {
  __shared__ int cnt[256];
  __shared__ int sc[256];
  __shared__ int cur[256];
  int b = blockIdx.x, tid = threadIdx.x;
  int node0 = b << BKT_SHIFT;
  int eb0 = bbase[b];
  int ebn = bcnt[b];
  cnt[tid] = 0;
  __syncthreads();
  for (int i = tid; i < ebn; i += 256) atomicAdd(&cnt[part[eb0 + i] >> 24], 1);
  __syncthreads();
  int v = cnt[tid];
  sc[tid] = v;
  __syncthreads();
  for (int dd = 1; dd < 256; dd <<= 1) {
    int x = (tid >= dd) ? sc[tid - dd] : 0;
    __syncthreads();
    sc[tid] += x;
    __syncthreads();
  }
  int lo = sc[tid] - v;  // exclusive
  cur[tid] = lo;
  int node = node0 + tid;
  if (node < n) {
    off[node] = eb0 + lo;
    end[node] = eb0 + lo + v;
    dis[node] = rsqrtf((float)v + 1.0f);
  }
  __syncthreads();
  for (int i = tid; i < ebn; i += 256) {
    unsigned int u = part[eb0 + i];
    int r = atomicAdd(&cur[u >> 24], 1);
    csr[eb0 + r] = (int)(u & 0xFFFFFFu);
  }
}

// Pre-split W (K x NOUT, f32) into k-step-blocked bf16 hi/lo:
//   Wsp[ks][hl][g][n][8] ; k = ks*32 + g*8 + j
template<int K, int NOUT>
__global__ __launch_bounds__(256) void k_split_w(const float* __restrict__ W,
                                                 __bf16* __restrict__ Wsp) {
  constexpr int KSTEPS = K / 32;
  int idx = blockIdx.x * 256 + threadIdx.x;  // (ks, g, n)
  if (idx >= KSTEPS * 4 * NOUT) return;
  int n = idx % NOUT;
  int g = (idx / NOUT) & 3;
  int ks = idx / (4 * NOUT);
  __bf16* hi = Wsp + (size_t)ks * (2 * 4 * NOUT * 8) + ((size_t)g * NOUT + n) * 8;
  __bf16* lo = hi + 4 * NOUT * 8;
#pragma unroll
  for (int j = 0; j < 8; ++j) {
    float f = W[(size_t)(ks * 32 + g * 8 + j) * NOUT + n];
    __bf16 h = (__bf16)f;
    hi[j] = h;
    lo[j] = (__bf16)(f - (float)h);
  }
}

// MFMA split-bf16 GEMM: T[m] = bf16( dis[m] * (X'[m] @ W) ), X' = relu(X+inb) if flagged.
// BM=128, 4 waves x 32 rows, full NOUT width. B staged in LDS (double buffer),
// A loaded direct from global per lane and split in-register.
template<int K, int NOUT, bool IN_RELU_BIAS>
__global__ __launch_bounds__(256) void k_gemm_mfma(
    const float* __restrict__ X, const __bf16* __restrict__ Wsp,
    const float* __restrict__ inb, const float* __restrict__ dis,
    __bf16* __restrict__ T, int M) {
  constexpr int BM = 128;
  constexpr int NF = NOUT / 16;        // n-frags per wave
  constexpr int KSTEPS = K / 32;
  constexpr int TILE = 2 * 4 * NOUT * 8;   // bf16 elems per kstep (hi+lo)
  constexpr int GRAN = TILE * 2 / 16;      // 16B granules per kstep
  constexpr int GPT = GRAN / 256;          // granules per thread
  __shared__ __bf16 blds[2][TILE];

  const int tid = threadIdx.x;
  const int wave = tid >> 6;
  const int lane = tid & 63;
  const int l15 = lane & 15;
  const int lg = lane >> 4;                 // k-group 0..3
  const int r0w = blockIdx.x * BM + wave * 32;

  f32x4 acc[2][NF];
#pragma unroll
  for (int mf = 0; mf < 2; ++mf)
#pragma unroll
    for (int nf = 0; nf < NF; ++nf) acc[mf][nf] = (f32x4){0.f, 0.f, 0.f, 0.f};

  int rowA[2];
#pragma unroll
  for (int mf = 0; mf < 2; ++mf) {
    int r = r0w + mf * 16 + l15;
    rowA[mf] = (r < M) ? r : (M - 1);  // clamp: OOB rows never stored
  }

  const uint4* gW = (const uint4*)Wsp;
  // prologue: stage kstep 0 into buf 0
  {
    uint4* dst4 = (uint4*)&blds[0][0];
#pragma unroll
    for (int i = 0; i < GPT; ++i) dst4[tid + i * 256] = gW[tid + i * 256];
  }
  __syncthreads();

  int cur = 0;
  for (int ks = 0; ks < KSTEPS; ++ks) {
    uint4 sreg[GPT];
    if (ks + 1 < KSTEPS) {
#pragma unroll
      for (int i = 0; i < GPT; ++i)
        sreg[i] = gW[(size_t)(ks + 1) * GPT * 256 + tid + i * 256];
    }
    // ---- A fragments: load f32, optional relu+bias, split hi/lo in regs
    bf16x8 ah[2], al[2];
    const int k0 = ks * 32 + lg * 8;
#pragma unroll
    for (int mf = 0; mf < 2; ++mf) {
      const float* ap = X + (size_t)rowA[mf] * K + k0;
      float4 v0 = *(const float4*)ap;
      float4 v1 = *(const float4*)(ap + 4);
      float va[8] = {v0.x, v0.y, v0.z, v0.w, v1.x, v1.y, v1.z, v1.w};
      if (IN_RELU_BIAS) {
        float4 bb0 = *(const float4*)(inb + k0);
        float4 bb1 = *(const float4*)(inb + k0 + 4);
        float bb[8] = {bb0.x, bb0.y, bb0.z, bb0.w, bb1.x, bb1.y, bb1.z, bb1.w};
#pragma unroll
        for (int j = 0; j < 8; ++j) va[j] = fmaxf(va[j] + bb[j], 0.f);
      }
#pragma unroll
      for (int j = 0; j < 8; ++j) {
        __bf16 h = (__bf16)va[j];
        ah[mf][j] = h;
        al[mf][j] = (__bf16)(va[j] - (float)h);
      }
    }
    // ---- B fragments from LDS + MFMA (3-term split)
    const __bf16* bh_base = &blds[cur][0];
    const __bf16* bl_base = &blds[cur][4 * NOUT * 8];
    const int boff = lg * NOUT * 8 + l15 * 8;
#pragma unroll
    for (int nf = 0; nf < NF; ++nf) {
      bf16x8 bh = *(const bf16x8*)(bh_base + boff + nf * 128);
      bf16x8 bl = *(const bf16x8*)(bl_base + boff + nf * 128);
#pragma unroll
      for (int mf = 0; mf < 2; ++mf) {
        acc[mf][nf] = __builtin_amdgcn_mfma_f32_16x16x32_bf16(ah[mf], bh, acc[mf][nf], 0, 0, 0);
        acc[mf][nf] = __builtin_amdgcn_mfma_f32_16x16x32_bf16(ah[mf], bl, acc[mf][nf], 0, 0, 0);
        acc[mf][nf] = __builtin_amdgcn_mfma_f32_16x16x32_bf16(al[mf], bh, acc[mf][nf], 0, 0, 0);
      }
    }
    if (ks + 1 < KSTEPS) {
      uint4* dst4 = (uint4*)&blds[cur ^ 1][0];
#pragma unroll
      for (int i = 0; i < GPT; ++i) dst4[tid + i * 256] = sreg[i];
    }
    __syncthreads();
    cur ^= 1;
  }

  // ---- epilogue: C[col=l15, row=lg*4+r]; T[m] = bf16(dis[m] * acc)
#pragma unroll
  for (int mf = 0; mf < 2; ++mf) {
    int rbase = r0w + mf * 16 + lg * 4;
    float dv[4];
#pragma unroll
    for (int r = 0; r < 4; ++r) dv[r] = (rbase + r < M) ? dis[rbase + r] : 0.f;
#pragma unroll
    for (int nf = 0; nf < NF; ++nf) {
#pragma unroll
      for (int r = 0; r < 4; ++r) {
        int rr = rbase + r;
        if (rr < M) T[(size_t)rr * NOUT + nf * 16 + l15] = (__bf16)(dv[r] * acc[mf][nf][r]);
      }
    }
  }
}

// CSR gather aggregation over bf16 table: wave per node, G lane-groups of LPG
// lanes; each lane loads bf16x8 (16B), accumulates f32; shfl_xor group fold.
// out[i] = dis[i] * (sum ts[s] + ts[i]) (+ bias), written f32.
template<int C, bool BIAS>
__global__ __launch_bounds__(256) void k_agg_csr(
    const int* __restrict__ csr, const int* __restrict__ off,
    const int* __restrict__ end, const __bf16* __restrict__ ts,
    const float* __restrict__ dis, const float* __restrict__ bias,
    float* __restrict__ out, int n) {
  constexpr int LPG = C / 8;   // lanes per group: 16 (C=128), 8 (C=64)
  constexpr int G = 64 / LPG;  // groups per wave: 4, 8
  int wid = (blockIdx.x * 256 + threadIdx.x) >> 6;
  int lane = threadIdx.x & 63;
  int gid = lane / LPG;
  int gl = lane % LPG;
  if (wid >= n) return;

  float acc[8];
#pragma unroll
  for (int j = 0; j < 8; ++j) acc[j] = 0.f;
  if (gid == 0) {  // self term
    bf16x8 v = *(const bf16x8*)(ts + (size_t)wid * C + gl * 8);
#pragma unroll
    for (int j = 0; j < 8; ++j) acc[j] = (float)v[j];
  }

  int e = off[wid] + gid;
  int e1 = end[wid];
  for (; e + G < e1; e += 2 * G) {
    int s0 = csr[e];
    int s1 = csr[e + G];
    bf16x8 v0 = *(const bf16x8*)(ts + (size_t)s0 * C + gl * 8);
    bf16x8 v1 = *(const bf16x8*)(ts + (size_t)s1 * C + gl * 8);
#pragma unroll
    for (int j = 0; j < 8; ++j) acc[j] += (float)v0[j] + (float)v1[j];
  }
  if (e < e1) {
    int s0 = csr[e];
    bf16x8 v0 = *(const bf16x8*)(ts + (size_t)s0 * C + gl * 8);
#pragma unroll
    for (int j = 0; j < 8; ++j) acc[j] += (float)v0[j];
  }

  // cross-group reduce: fold groups down to lanes [0, LPG)
#pragma unroll
  for (int w = LPG; w < 64; w <<= 1) {
#pragma unroll
    for (int j = 0; j < 8; ++j) acc[j] += __shfl_xor(acc[j], w);
  }

  if (gid == 0) {
    float di = dis[wid];
    float o[8];
#pragma unroll
    for (int j = 0; j < 8; ++j) {
      o[j] = di * acc[j];
      if (BIAS) o[j] += bias[gl * 8 + j];
    }
    float4* op = (float4*)(out + (size_t)wid * C + gl * 8);
    op[0] = make_float4(o[0], o[1], o[2], o[3]);
    op[1] = make_float4(o[4], o[5], o[6], o[7]);
  }
}

extern "C" void kernel_launch(void* const* d_in, const int* in_sizes, int n_in,
                              void* d_out, int out_size, void* d_ws, size_t ws_size,
                              hipStream_t stream) {
  const float* x  = (const float*)d_in[0];
  const int*   ei = (const int*)d_in[1];
  const float* W1 = (const float*)d_in[2];
  const float* b1 = (const float*)d_in[3];
  const float* W2 = (const float*)d_in[4];
  const float* b2 = (const float*)d_in[5];
  float* out = (float*)d_out;

  const int N = in_sizes[0] / GCN_IN_C;  // 100000
  const int E = in_sizes[1] / 2;         // 1600000
  const int* src = ei;
  const int* dst = ei + E;
  const int NB = (N + BKT_NODES - 1) >> BKT_SHIFT;  // 391 buckets
  const int EB = (E + EPB - 1) / EPB;               // partition blocks

  // ws layout:
  //   dis[N] | t1s(bf16)[N*128] | a1(f32)[N*128] | off[N] | end[N] | csr[E]
  //   | bcnt|bbase|bcur [512 each] | w1sp | w2sp
  //   part[E] aliases a1 (dead before agg1 writes a1)
  char* p = (char*)d_ws;
  float* dis = (float*)p;             p += (size_t)N * 4;
  __bf16* t1s = (__bf16*)p;           p += (size_t)N * GCN_HID * 2;
  float* a1  = (float*)p;             p += (size_t)N * GCN_HID * 4;
  int* off   = (int*)p;               p += (size_t)N * 4;
  int* end   = (int*)p;               p += (size_t)N * 4;
  int* csr   = (int*)p;               p += (size_t)E * 4;
  int* bcnt  = (int*)p;               p += 512 * 4;
  int* bbase = (int*)p;               p += 512 * 4;
  int* bcur  = (int*)p;               p += 512 * 4;
  __bf16* w1sp = (__bf16*)p;          p += (size_t)(GCN_IN_C / 32) * 2 * 4 * GCN_HID * 8 * 2;
  __bf16* w2sp = (__bf16*)p;
  unsigned int* part = (unsigned int*)a1;  // alias
  __bf16* t2s = t1s;  // layer-2 table reuses layer-1 table (row stride 64)

  // ---- weight pre-split (bf16 hi/lo, k-step-blocked)
  k_split_w<GCN_IN_C, GCN_HID>
      <<<((GCN_IN_C / 32) * 4 * GCN_HID + 255) / 256, 256, 0, stream>>>(W1, w1sp);
  k_split_w<GCN_HID, GCN_OUT>
      <<<((GCN_HID / 32) * 4 * GCN_OUT + 255) / 256, 256, 0, stream>>>(W2, w2sp);

  // ---- CSR build (bucketed counting sort)
  k_zero_i32<<<2, 256, 0, stream>>>(bcnt, 512);
  k_bucket_hist<<<EB, 256, 0, stream>>>(dst, bcnt, E, NB);
  k_scan_buckets<<<1, 512, 0, stream>>>(bcnt, bbase, bcur, NB);
  k_partition<<<EB, 256, 0, stream>>>(src, dst, bcur, part, E, NB);
  k_bucket_csr<<<NB, 256, 0, stream>>>(part, bbase, bcnt, off, end, dis, csr, N);

  // ---- layer 1
  k_gemm_mfma<GCN_IN_C, GCN_HID, false>
      <<<(N + 127) / 128, 256, 0, stream>>>(x, w1sp, nullptr, dis, t1s, N);
  k_agg_csr<GCN_HID, false>
      <<<((size_t)N * 64 + 255) / 256, 256, 0, stream>>>(csr, off, end, t1s, dis, nullptr, a1, N);

  // ---- layer 2
  k_gemm_mfma<GCN_HID, GCN_OUT, true>
      <<<(N + 127) / 128, 256, 0, stream>>>(a1, w2sp, b1, dis, t2s, N);
  k_agg_csr<GCN_OUT, true>
      <<<((size_t)N * 64 + 255) / 256, 256, 0, stream>>>(csr, off, end, t2s, dis, b2, out, N);
}